// Round 20
// baseline (241.355 us; speedup 1.0000x reference)
//
#include <hip/hip_runtime.h>
#include <hip/hip_bf16.h>
#include <hip/hip_fp16.h>

#define N_NODES 50000
#define HEADS 4
#define DHEAD 32
#define F 128           // HEADS*DHEAD = in/out feature width everywhere
#define NEG_SLOPE 0.2f
#define MAXD 64         // LDS-stash fast-path degree bound
#define SCH 2048        // scatter: edges per block chunk
#define NCHUNK 64       // hist: edge chunks (per-node partial count — scanA cost)
#define NRANGE 16       // hist: node ranges (parallelism; dst is L2-resident)
#define RSZ_MAX 3136    // max nodes per range (N/16 = 3125)

typedef unsigned int uint;
typedef unsigned short ushort;
typedef __attribute__((ext_vector_type(8))) short bf16x8;
typedef __attribute__((ext_vector_type(4))) float f32x4;

__device__ __forceinline__ float bf2f(ushort u) {
    union { uint i; float f; } c; c.i = ((uint)u) << 16; return c.f;
}
__device__ __forceinline__ ushort f2bf(float f) {
    union { float f; uint i; } c; c.f = f;
    uint u = c.i + 0x7FFF + ((c.i >> 16) & 1);   // round-to-nearest-even
    return (ushort)(u >> 16);
}
__device__ __forceinline__ float sel4(int h, float a, float b, float c, float d) {
    return (h & 2) ? ((h & 1) ? d : c) : ((h & 1) ? b : a);
}

// ---------------------------------------------------------------------------
// Weight transpose + W-projected ALR tables (tiny, runs before the fused
// hist+GEMM1 dispatch so WT1/ALR1 are ready).
// ---------------------------------------------------------------------------
__global__ __launch_bounds__(256) void wtrans_kernel(
    const float* __restrict__ W1, const float* __restrict__ W2,
    const float* __restrict__ Wp,
    const float* __restrict__ al1, const float* __restrict__ ar1,
    const float* __restrict__ al2, const float* __restrict__ ar2,
    ushort* __restrict__ WT) {
    int bid = blockIdx.x;
    if (bid < 3) {
        const float* W = (bid == 0) ? W1 : (bid == 1) ? W2 : Wp;
        ushort* T = WT + (size_t)bid * 128 * 128;
        for (int i = threadIdx.x; i < 128 * 128; i += 256) {
            int r = i >> 7, c = i & 127;
            T[c * 128 + r] = f2bf(W[i]);
        }
    } else {
        const float* W   = (bid == 3) ? W1 : W2;
        const float* a_l = (bid == 3) ? al1 : al2;
        const float* a_r = (bid == 3) ? ar1 : ar2;
        ushort* T = WT + 3 * 128 * 128 + (bid - 3) * 16 * 128;
        for (int i = threadIdx.x; i < 16 * 128; i += 256) {
            int c = i >> 7, k = i & 127;
            float v = 0.f;
            if (c < 8) {
                int h = c & 3;
                const float* a  = (c < 4) ? (a_l + h * 32) : (a_r + h * 32);
                const float* wr = W + k * 128 + h * 32;
#pragma unroll
                for (int d = 0; d < 32; d++) v += wr[d] * a[d];
            }
            T[i] = f2bf(v);
        }
    }
}

// ---------------------------------------------------------------------------
// MFMA GEMM body: C[M,128] = A[M,128] @ B[128,128], B transposed bf16.
// One "block" (bx) = 4 waves, each wave 16 rows x 128 cols.
// ELER: one extra 16x16x32 MFMA chain vs the W-projected ALR table computes
// el (cols 0-3) and er (cols 4-7) for the wave's 16 rows.
// ---------------------------------------------------------------------------
template <bool A_FP32, bool OUT_BF16, bool BIAS, bool ELER>
__device__ __forceinline__ void mfma_gemm_body(
    int bx, const void* __restrict__ Av, const ushort* __restrict__ BT,
    const float* __restrict__ bias, const ushort* __restrict__ ALR,
    void* __restrict__ Cv, float* __restrict__ el, float* __restrict__ er, int M) {
    int wid = threadIdx.x >> 6;
    int lane = threadIdx.x & 63;
    int row0 = bx * 64 + wid * 16;
    int rsub = lane & 15;
    int kg = lane >> 4;
    int row = row0 + rsub;
    int rowc = (row < M) ? row : (M - 1);

    bf16x8 af[4];
    if (A_FP32) {
        const float* A = (const float*)Av;
        const float* ap = A + (size_t)rowc * 128 + kg * 8;
#pragma unroll
        for (int ks = 0; ks < 4; ks++) {
            float4 lo = *(const float4*)(ap + ks * 32);
            float4 hi = *(const float4*)(ap + ks * 32 + 4);
            bf16x8 v;
            v[0] = (short)f2bf(lo.x); v[1] = (short)f2bf(lo.y);
            v[2] = (short)f2bf(lo.z); v[3] = (short)f2bf(lo.w);
            v[4] = (short)f2bf(hi.x); v[5] = (short)f2bf(hi.y);
            v[6] = (short)f2bf(hi.z); v[7] = (short)f2bf(hi.w);
            af[ks] = v;
        }
    } else {
        const ushort* A = (const ushort*)Av;
        const ushort* ap = A + (size_t)rowc * 128 + kg * 8;
#pragma unroll
        for (int ks = 0; ks < 4; ks++) af[ks] = *(const bf16x8*)(ap + ks * 32);
    }

    f32x4 acc[8];
#pragma unroll
    for (int ct = 0; ct < 8; ct++) acc[ct] = (f32x4){0.f, 0.f, 0.f, 0.f};

    const ushort* bp = BT + (size_t)rsub * 128 + kg * 8;
#pragma unroll
    for (int ks = 0; ks < 4; ks++) {
#pragma unroll
        for (int ct = 0; ct < 8; ct++) {
            bf16x8 bf = *(const bf16x8*)(bp + (size_t)ct * 16 * 128 + ks * 32);
            acc[ct] = __builtin_amdgcn_mfma_f32_16x16x32_bf16(af[ks], bf, acc[ct], 0, 0, 0);
        }
    }

    f32x4 acce = (f32x4){0.f, 0.f, 0.f, 0.f};
    if (ELER) {
        const ushort* ep = ALR + rsub * 128 + kg * 8;
#pragma unroll
        for (int ks = 0; ks < 4; ks++) {
            bf16x8 eb = *(const bf16x8*)(ep + ks * 32);
            acce = __builtin_amdgcn_mfma_f32_16x16x32_bf16(af[ks], eb, acce, 0, 0, 0);
        }
    }

    if (row0 >= M) return;

#pragma unroll
    for (int ct = 0; ct < 8; ct++) {
        int col = ct * 16 + rsub;
        float bv = BIAS ? bias[col] : 0.f;
#pragma unroll
        for (int r = 0; r < 4; r++) {
            int gr = row0 + kg * 4 + r;
            if (gr < M) {
                float v = acc[ct][r] + bv;
                if (OUT_BF16) ((ushort*)Cv)[(size_t)gr * 128 + col] = f2bf(v);
                else          ((float*)Cv)[(size_t)gr * 128 + col] = v;
            }
        }
    }

    if (ELER && rsub < 8) {
#pragma unroll
        for (int r = 0; r < 4; r++) {
            int gr = row0 + kg * 4 + r;
            if (gr < M) {
                if (rsub < 4) el[(size_t)gr * 4 + rsub] = acce[r];
                else          er[(size_t)gr * 4 + (rsub - 4)] = acce[r];
            }
        }
    }
}

template <bool A_FP32, bool OUT_BF16, bool BIAS, bool ELER>
__global__ __launch_bounds__(256) void mfma_gemm_kernel(
    const void* __restrict__ Av, const ushort* __restrict__ BT,
    const float* __restrict__ bias, const ushort* __restrict__ ALR,
    void* __restrict__ Cv, float* __restrict__ el, float* __restrict__ er, int M) {
    mfma_gemm_body<A_FP32, OUT_BF16, BIAS, ELER>(blockIdx.x, Av, BT, bias, ALR,
                                                 Cv, el, er, M);
}

// ---------------------------------------------------------------------------
// Fused hist + GEMM1: blocks < NRANGE*NCHUNK run the per-(range,chunk) LDS
// histogram (atomic-free CSR rank build — global atomics are HBM-level RMWs
// on gfx950); remaining blocks run layer-1 GEMM(+el/er). Independent work
// overlapped in one dispatch: GEMM's MFMA hides under hist's latency stalls.
// ---------------------------------------------------------------------------
__global__ __launch_bounds__(256) void hist_gemm1_kernel(
    const int* __restrict__ dst, int* __restrict__ parthist,
    int* __restrict__ lrank,
    const float* __restrict__ x, const ushort* __restrict__ WT1,
    const ushort* __restrict__ ALR1, ushort* __restrict__ featb,
    float* __restrict__ el, float* __restrict__ er,
    int E, int N, int CH, int RSZ, int M) {
    __shared__ int lhist[RSZ_MAX];
    if (blockIdx.x < (uint)(NRANGE * NCHUNK)) {
        int r = blockIdx.x & (NRANGE - 1);
        int c = blockIdx.x >> 4;                 // log2(NRANGE)=4
        int nlo = r * RSZ;
        int nhi = nlo + RSZ; if (nhi > N) nhi = N;
        for (int j = threadIdx.x; j < RSZ; j += 256) lhist[j] = 0;
        __syncthreads();
        int lo = c * CH, hi = lo + CH; if (hi > E) hi = E;
        for (int i = lo + threadIdx.x; i < hi; i += 256) {
            int d = dst[i];
            if (d >= nlo && d < nhi) lrank[i] = atomicAdd(&lhist[d - nlo], 1);
        }
        __syncthreads();
        int* ph = parthist + (size_t)(r * NCHUNK + c) * RSZ;
        for (int j = threadIdx.x; j < RSZ; j += 256) ph[j] = lhist[j];
        return;
    }
    mfma_gemm_body<true, true, false, true>(blockIdx.x - NRANGE * NCHUNK,
                                            x, WT1, nullptr, ALR1,
                                            featb, el, er, M);
}

// per-node chunk-prefix + degree, then block scan -> offs partial
__global__ __launch_bounds__(256) void scanA_kernel(int* __restrict__ parthist,
                                                    int* __restrict__ local_sc,
                                                    int* __restrict__ partials,
                                                    int N, int RSZ) {
    int i = blockIdx.x * 256 + threadIdx.x;
    int deg = 0;
    if (i < N) {
        int r = i / RSZ;
        int li = i - r * RSZ;
        size_t base = (size_t)(r * NCHUNK) * RSZ + li;
        for (int c = 0; c < NCHUNK; c++) {
            size_t idx = base + (size_t)c * RSZ;
            int t = parthist[idx];
            parthist[idx] = deg;
            deg += t;
        }
    }
    int lane = threadIdx.x & 63;
    int w = threadIdx.x >> 6;
    int x = deg;
#pragma unroll
    for (int off = 1; off < 64; off <<= 1) {
        int t = __shfl_up(x, off);
        if (lane >= off) x += t;
    }
    __shared__ int wsum[4];
    if (lane == 63) wsum[w] = x;
    __syncthreads();
    int wpre = 0;
#pragma unroll
    for (int k = 0; k < 4; k++)
        if (k < w) wpre += wsum[k];
    if (i < N) local_sc[i] = x - deg + wpre;
    if (threadIdx.x == 255) partials[blockIdx.x] = wpre + x;
}

__global__ void scanB_kernel(int* __restrict__ partials, int NP) {
    int tid = threadIdx.x;
    int v = (tid < NP) ? partials[tid] : 0;
    int lane = tid & 63;
    int w = tid >> 6;
    int x = v;
#pragma unroll
    for (int off = 1; off < 64; off <<= 1) {
        int t = __shfl_up(x, off);
        if (lane >= off) x += t;
    }
    __shared__ int wsum[4];
    if (lane == 63) wsum[w] = x;
    __syncthreads();
    int wpre = 0;
#pragma unroll
    for (int k = 0; k < 4; k++)
        if (k < w) wpre += wsum[k];
    if (tid < NP) partials[tid] = x - v + wpre;
}

__global__ __launch_bounds__(256) void scanC_kernel(int* __restrict__ offs,
                                                    const int* __restrict__ partials,
                                                    int N, int E) {
    int i = blockIdx.x * 256 + threadIdx.x;
    if (i < N) offs[i] += partials[blockIdx.x];
    if (i == 0) offs[N] = E;
}

__global__ void posfix_kernel(const int* __restrict__ dst,
                              const int* __restrict__ offs,
                              const int* __restrict__ parthist,
                              int* __restrict__ lrank, int E, int CH, int RSZ) {
    int i = blockIdx.x * 256 + threadIdx.x;
    if (i < E) {
        int d = dst[i];
        int c = i / CH;
        int r = d / RSZ;
        int li = d - r * RSZ;
        lrank[i] += offs[d] + parthist[(size_t)(r * NCHUNK + c) * RSZ + li];
    }
}

__global__ __launch_bounds__(256) void scatter_ranged_kernel(
    const int* __restrict__ src, const int* __restrict__ pos,
    int* __restrict__ csr_src, int E) {
    int range = blockIdx.x & 7;
    int chunk = blockIdx.x >> 3;
    int base = chunk * SCH + threadIdx.x;
    int lo = (int)(((long long)range * E) >> 3);
    int hi = (int)(((long long)(range + 1) * E) >> 3);
#pragma unroll
    for (int k = 0; k < SCH / 256; k++) {
        int i = base + k * 256;
        if (i < E) {
            int p = pos[i];
            if (p >= lo && p < hi) csr_src[p] = src[i];
        }
    }
}

// ---------------------------------------------------------------------------
// Aggregate (R17/R19-proven): 16 lanes per node (4 nodes/wave, 16 nodes/
// block). Fast path (deg<=64): pass1 stashes (sv, fp16 leaky-logit[4]) in LDS
// during the online softmax; after the reduce each lane converts its stashed
// logits to FINAL fp16 ALPHAS in LDS. Pass2: 8-edge batches — alpha from LDS
// + 8 independent 16B feat gathers; no exp in loop. Slow path: 4-edge shfl.
// ---------------------------------------------------------------------------
template <bool F32OUT>
__global__ __launch_bounds__(256) void aggregate_kernel(
    const ushort* __restrict__ featb, const float* __restrict__ el,
    const float* __restrict__ er, const float* __restrict__ bias,
    const int* __restrict__ offsets, const int* __restrict__ csr_src,
    void* __restrict__ outv, int N) {
    __shared__ int    s_sv[16][MAXD + 1];       // +1 pad: group stride 65
    __shared__ __half s_lg[16][MAXD + 1][4];    // fp16 logits -> alphas
    int tid = threadIdx.x;
    int gl = tid & 15;
    int g  = tid >> 4;
    int lane = tid & 63;
    int n = blockIdx.x * 16 + g;
    if (n >= N) return;
    int start = offsets[n], end = offsets[n + 1];
    int deg = end - start;
    bool fast = (deg <= MAXD);

    float4 erv = *(const float4*)(er + (size_t)n * 4);
    float er_h[4] = {erv.x, erv.y, erv.z, erv.w};

    float m[4], s[4];
#pragma unroll
    for (int h = 0; h < 4; h++) { m[h] = -1e30f; s[h] = 0.f; }

    for (int e = start + gl; e < end; e += 16) {
        int sv = csr_src[e];
        float4 ev = *(const float4*)(el + (size_t)sv * 4);
        float elh[4] = {ev.x, ev.y, ev.z, ev.w};
        int idx = e - start;
        if (fast) s_sv[g][idx] = sv;
#pragma unroll
        for (int h = 0; h < 4; h++) {
            float v = elh[h] + er_h[h];
            v = (v >= 0.f) ? v : NEG_SLOPE * v;
            if (fast) s_lg[g][idx][h] = __float2half(v);
            float mn = fmaxf(m[h], v);
            s[h] = s[h] * __expf(m[h] - mn) + __expf(v - mn);
            m[h] = mn;
        }
    }
#pragma unroll
    for (int off = 1; off < 16; off <<= 1) {
#pragma unroll
        for (int h = 0; h < 4; h++) {
            float mo = __shfl_xor(m[h], off);
            float so = __shfl_xor(s[h], off);
            float mn = fmaxf(m[h], mo);
            s[h] = s[h] * __expf(m[h] - mn) + so * __expf(mo - mn);
            m[h] = mn;
        }
    }

    int h0 = gl >> 2;
    int c0 = gl * 8;
    float acc[8] = {};

    if (fast) {
        float rz[4];
#pragma unroll
        for (int h = 0; h < 4; h++) rz[h] = (deg > 0) ? 1.0f / s[h] : 0.f;
        for (int e = gl; e < deg; e += 16) {
#pragma unroll
            for (int h = 0; h < 4; h++) {
                float lg = __half2float(s_lg[g][e][h]);
                s_lg[g][e][h] = __float2half(__expf(lg - m[h]) * rz[h]);
            }
        }
        for (int e0 = 0; e0 < deg; e0 += 8) {
            int nb = deg - e0; if (nb > 8) nb = 8;
            float av[8]; int svv[8];
#pragma unroll
            for (int jj = 0; jj < 8; jj++) {
                int idx = (jj < nb) ? (e0 + jj) : e0;
                svv[jj] = s_sv[g][idx];
                av[jj] = (jj < nb) ? __half2float(s_lg[g][idx][h0]) : 0.f;
            }
#pragma unroll
            for (int jj = 0; jj < 8; jj++) {
                uint4 f0 = *(const uint4*)(featb + (size_t)svv[jj] * 128 + c0);
                acc[0] = fmaf(av[jj], bf2f(f0.x & 0xFFFF), acc[0]);
                acc[1] = fmaf(av[jj], bf2f(f0.x >> 16),    acc[1]);
                acc[2] = fmaf(av[jj], bf2f(f0.y & 0xFFFF), acc[2]);
                acc[3] = fmaf(av[jj], bf2f(f0.y >> 16),    acc[3]);
                acc[4] = fmaf(av[jj], bf2f(f0.z & 0xFFFF), acc[4]);
                acc[5] = fmaf(av[jj], bf2f(f0.z >> 16),    acc[5]);
                acc[6] = fmaf(av[jj], bf2f(f0.w & 0xFFFF), acc[6]);
                acc[7] = fmaf(av[jj], bf2f(f0.w >> 16),    acc[7]);
            }
        }
    } else {
        float mh  = sel4(h0, m[0], m[1], m[2], m[3]);
        float sh  = sel4(h0, s[0], s[1], s[2], s[3]);
        float rzh = (deg > 0) ? 1.0f / sh : 0.f;
        int j = gl & 3;
        float erh = sel4(h0, er_h[0], er_h[1], er_h[2], er_h[3]);
        int bidx = lane & 60;
        for (int e = start; e < end; e += 4) {
            int rem = end - e;
            int ej = e + ((j < rem) ? j : 0);
            int svj = csr_src[ej];
            float v = el[(size_t)svj * 4 + h0] + erh;
            v = (v >= 0.f) ? v : NEG_SLOPE * v;
            float a = __expf(v - mh) * rzh;
            if (j >= rem) a = 0.f;
#pragma unroll
            for (int jj = 0; jj < 4; jj++) {
                float ajj = __shfl(a, bidx | jj);
                int svjj  = __shfl(svj, bidx | jj);
                uint4 f0 = *(const uint4*)(featb + (size_t)svjj * 128 + c0);
                acc[0] = fmaf(ajj, bf2f(f0.x & 0xFFFF), acc[0]);
                acc[1] = fmaf(ajj, bf2f(f0.x >> 16),    acc[1]);
                acc[2] = fmaf(ajj, bf2f(f0.y & 0xFFFF), acc[2]);
                acc[3] = fmaf(ajj, bf2f(f0.y >> 16),    acc[3]);
                acc[4] = fmaf(ajj, bf2f(f0.z & 0xFFFF), acc[4]);
                acc[5] = fmaf(ajj, bf2f(f0.z >> 16),    acc[5]);
                acc[6] = fmaf(ajj, bf2f(f0.w & 0xFFFF), acc[6]);
                acc[7] = fmaf(ajj, bf2f(f0.w >> 16),    acc[7]);
            }
        }
    }

    float4 b0 = *(const float4*)(bias + c0);
    float4 b1 = *(const float4*)(bias + c0 + 4);
    float o[8];
    o[0] = acc[0] + b0.x; o[1] = acc[1] + b0.y; o[2] = acc[2] + b0.z; o[3] = acc[3] + b0.w;
    o[4] = acc[4] + b1.x; o[5] = acc[5] + b1.y; o[6] = acc[6] + b1.z; o[7] = acc[7] + b1.w;
    if (F32OUT) {
        float* outf = (float*)outv;
        float4 w0, w1;
        w0.x = o[0]; w0.y = o[1]; w0.z = o[2]; w0.w = o[3];
        w1.x = o[4]; w1.y = o[5]; w1.z = o[6]; w1.w = o[7];
        *(float4*)(outf + (size_t)n * 128 + c0) = w0;
        *(float4*)(outf + (size_t)n * 128 + c0 + 4) = w1;
    } else {
        ushort* outb = (ushort*)outv;
        uint4 p;
        p.x = (uint)f2bf(o[0]) | ((uint)f2bf(o[1]) << 16);
        p.y = (uint)f2bf(o[2]) | ((uint)f2bf(o[3]) << 16);
        p.z = (uint)f2bf(o[4]) | ((uint)f2bf(o[5]) << 16);
        p.w = (uint)f2bf(o[6]) | ((uint)f2bf(o[7]) << 16);
        *(uint4*)(outb + (size_t)n * 128 + c0) = p;
    }
}

// ---------------------------------------------------------------------------
extern "C" void kernel_launch(void* const* d_in, const int* in_sizes, int n_in,
                              void* d_out, int out_size, void* d_ws, size_t ws_size,
                              hipStream_t stream) {
    const float* x   = (const float*)d_in[0];
    const int*   src = (const int*)d_in[1];
    const int*   dst = (const int*)d_in[2];
    const float* W1  = (const float*)d_in[3];
    const float* al1 = (const float*)d_in[4];
    const float* ar1 = (const float*)d_in[5];
    const float* b1  = (const float*)d_in[6];
    const float* W2  = (const float*)d_in[7];
    const float* al2 = (const float*)d_in[8];
    const float* ar2 = (const float*)d_in[9];
    const float* b2  = (const float*)d_in[10];
    const float* Wp  = (const float*)d_in[11];
    const float* bp  = (const float*)d_in[12];

    const int N = in_sizes[0] / F;      // 50000
    const int E = in_sizes[1];          // 800000

    float* h_out = (float*)d_out;               // [N,128]  (layer-2 output h, checked)
    float* p_out = h_out + (size_t)N * F;       // [N,128]  (projection output, checked)

    const int NB  = (N + 255) / 256;
    const int ECS = (E + SCH - 1) / SCH;            // scatter chunks
    const int CH  = (E + NCHUNK - 1) / NCHUNK;      // hist chunk size (12500)
    const int RSZ = (N + NRANGE - 1) / NRANGE;      // nodes per range (3125)

    // workspace carve
    char* w = (char*)d_ws;
    ushort* featb   = (ushort*)w;                               // N*128 bf16
    ushort* h1b     = featb + (size_t)N * F;                    // N*128 bf16
    float* el       = (float*)(h1b + (size_t)N * F);            // N*4
    float* er       = el + (size_t)N * 4;                       // N*4
    int*   offs     = (int*)(er + (size_t)N * 4);               // N+1
    int*   lrank    = offs + (N + 1);                           // E (becomes pos)
    int*   csrsrc   = lrank + E;                                // E
    int*   partials = csrsrc + E;                               // 256
    int*   parthist = partials + 256;                           // NRANGE*NCHUNK*RSZ
    ushort* WT      = (ushort*)(parthist + (size_t)NRANGE * NCHUNK * RSZ);

    ushort* WT1  = WT;
    ushort* WT2  = WT + 128 * 128;
    ushort* WTp  = WT + 2 * 128 * 128;
    ushort* ALR1 = WT + 3 * 128 * 128;
    ushort* ALR2 = ALR1 + 16 * 128;

    int ggrid = (N + 63) / 64;
    int agrid = (N + 15) / 16;

    // --- weight prep (tiny), then fused hist + layer-1 GEMM(+el/er) ---
    wtrans_kernel<<<5, 256, 0, stream>>>(W1, W2, Wp, al1, ar1, al2, ar2, WT);
    hist_gemm1_kernel<<<NRANGE * NCHUNK + ggrid, 256, 0, stream>>>(
        dst, parthist, lrank, x, WT1, ALR1, featb, el, er, E, N, CH, RSZ, N);

    // --- CSR scan chain ---
    scanA_kernel<<<NB, 256, 0, stream>>>(parthist, offs, partials, N, RSZ);
    scanB_kernel<<<1, 256, 0, stream>>>(partials, NB);
    scanC_kernel<<<NB, 256, 0, stream>>>(offs, partials, N, E);
    posfix_kernel<<<(E + 255) / 256, 256, 0, stream>>>(dst, offs, parthist, lrank, E, CH, RSZ);
    scatter_ranged_kernel<<<8 * ECS, 256, 0, stream>>>(src, lrank, csrsrc, E);

    // --- layer 1 aggregate ---
    aggregate_kernel<false><<<agrid, 256, 0, stream>>>(
        featb, el, er, b1, offs, csrsrc, h1b, N);

    // --- layer 2 (GEMM + MFMA el/er) ---
    mfma_gemm_kernel<false, true, false, true><<<ggrid, 256, 0, stream>>>(
        h1b, WT2, nullptr, ALR2, featb, el, er, N);
    aggregate_kernel<true><<<agrid, 256, 0, stream>>>(
        featb, el, er, b2, offs, csrsrc, h_out, N);

    // --- projection (reads fp32 h_out, converts to bf16 in-register) ---
    mfma_gemm_kernel<true, false, true, false><<<ggrid, 256, 0, stream>>>(
        h_out, WTp, bp, nullptr, p_out, nullptr, nullptr, N);
}

// Round 21
// 223.306 us; speedup vs baseline: 1.0808x; 1.0808x over previous
//
#include <hip/hip_runtime.h>
#include <hip/hip_bf16.h>

#define N_NODES 50000
#define HEADS 4
#define DHEAD 32
#define F 128           // HEADS*DHEAD = in/out feature width everywhere
#define NEG_SLOPE 0.2f
#define MAXD 64         // LDS-stash fast-path degree bound
#define SCH 2048        // scatter: edges per block chunk
#define NCHUNK 64       // hist: edge chunks per node-range
#define RSZ_MAX 6256    // max nodes per range (N/8, N=50000 -> 6250)

typedef unsigned int uint;
typedef unsigned short ushort;
typedef __attribute__((ext_vector_type(8))) short bf16x8;
typedef __attribute__((ext_vector_type(4))) float f32x4;

__device__ __forceinline__ float bf2f(ushort u) {
    union { uint i; float f; } c; c.i = ((uint)u) << 16; return c.f;
}
__device__ __forceinline__ ushort f2bf(float f) {
    union { float f; uint i; } c; c.f = f;
    uint u = c.i + 0x7FFF + ((c.i >> 16) & 1);   // round-to-nearest-even
    return (ushort)(u >> 16);
}
__device__ __forceinline__ float sel4(int h, float a, float b, float c, float d) {
    return (h & 2) ? ((h & 1) ? d : c) : ((h & 1) ? b : a);
}

// ---------------------------------------------------------------------------
// Atomic-free CSR build (global atomics are HBM-level RMWs on gfx950's
// non-coherent L2s — R15/R16 measured 25-28MB WRITE from 800k of them).
// Per-(range,chunk) LDS histograms instead:
//   hist_lds: block (r,c) counts dst hits of node-range r over edge-chunk c
//     in LDS (CU-local atomics), records lrank[i], flushes parthist[r][c][*].
//   scanA: per-node chunk-prefix (in place) + degree; hierarchical scan.
//   posfix: pos[i] = offs[d] + chunkpref[r][c][li] + lrank[i].
//   scatter_ranged: csr_src[pos] = src (one XCD owns each output window).
// ---------------------------------------------------------------------------
__global__ __launch_bounds__(256) void hist_lds_wtrans_kernel(
    const int* __restrict__ dst, int* __restrict__ parthist,
    int* __restrict__ lrank,
    const float* __restrict__ W1, const float* __restrict__ W2,
    const float* __restrict__ Wp,
    const float* __restrict__ al1, const float* __restrict__ ar1,
    const float* __restrict__ al2, const float* __restrict__ ar2,
    ushort* __restrict__ WT, int E, int N, int CH, int RSZ) {
    __shared__ int lhist[RSZ_MAX];
    if (blockIdx.x < (uint)(8 * NCHUNK)) {
        int r = blockIdx.x & 7;
        int c = blockIdx.x >> 3;
        int nlo = r * RSZ;
        int nhi = nlo + RSZ; if (nhi > N) nhi = N;
        for (int j = threadIdx.x; j < RSZ; j += 256) lhist[j] = 0;
        __syncthreads();
        int lo = c * CH, hi = lo + CH; if (hi > E) hi = E;
        for (int i = lo + threadIdx.x; i < hi; i += 256) {
            int d = dst[i];
            if (d >= nlo && d < nhi) lrank[i] = atomicAdd(&lhist[d - nlo], 1);
        }
        __syncthreads();
        int* ph = parthist + (size_t)(r * NCHUNK + c) * RSZ;
        for (int j = threadIdx.x; j < RSZ; j += 256) ph[j] = lhist[j];
        return;
    }
    int bid = blockIdx.x - 8 * NCHUNK;
    if (bid < 3) {
        const float* W = (bid == 0) ? W1 : (bid == 1) ? W2 : Wp;
        ushort* T = WT + (size_t)bid * 128 * 128;
        for (int i = threadIdx.x; i < 128 * 128; i += 256) {
            int r = i >> 7, c = i & 127;
            T[c * 128 + r] = f2bf(W[i]);
        }
    } else {
        const float* W   = (bid == 3) ? W1 : W2;
        const float* a_l = (bid == 3) ? al1 : al2;
        const float* a_r = (bid == 3) ? ar1 : ar2;
        ushort* T = WT + 3 * 128 * 128 + (bid - 3) * 16 * 128;
        for (int i = threadIdx.x; i < 16 * 128; i += 256) {
            int c = i >> 7, k = i & 127;
            float v = 0.f;
            if (c < 8) {
                int h = c & 3;
                const float* a  = (c < 4) ? (a_l + h * 32) : (a_r + h * 32);
                const float* wr = W + k * 128 + h * 32;
#pragma unroll
                for (int d = 0; d < 32; d++) v += wr[d] * a[d];
            }
            T[i] = f2bf(v);
        }
    }
}

__global__ __launch_bounds__(256) void scanA_kernel(int* __restrict__ parthist,
                                                    int* __restrict__ local_sc,
                                                    int* __restrict__ partials,
                                                    int N, int RSZ) {
    int i = blockIdx.x * 256 + threadIdx.x;
    int deg = 0;
    if (i < N) {
        int r = i / RSZ;
        int li = i - r * RSZ;
        size_t base = (size_t)(r * NCHUNK) * RSZ + li;
        for (int c = 0; c < NCHUNK; c++) {
            size_t idx = base + (size_t)c * RSZ;
            int t = parthist[idx];
            parthist[idx] = deg;
            deg += t;
        }
    }
    int lane = threadIdx.x & 63;
    int w = threadIdx.x >> 6;
    int x = deg;
#pragma unroll
    for (int off = 1; off < 64; off <<= 1) {
        int t = __shfl_up(x, off);
        if (lane >= off) x += t;
    }
    __shared__ int wsum[4];
    if (lane == 63) wsum[w] = x;
    __syncthreads();
    int wpre = 0;
#pragma unroll
    for (int k = 0; k < 4; k++)
        if (k < w) wpre += wsum[k];
    if (i < N) local_sc[i] = x - deg + wpre;
    if (threadIdx.x == 255) partials[blockIdx.x] = wpre + x;
}

__global__ void scanB_kernel(int* __restrict__ partials, int NP) {
    int tid = threadIdx.x;
    int v = (tid < NP) ? partials[tid] : 0;
    int lane = tid & 63;
    int w = tid >> 6;
    int x = v;
#pragma unroll
    for (int off = 1; off < 64; off <<= 1) {
        int t = __shfl_up(x, off);
        if (lane >= off) x += t;
    }
    __shared__ int wsum[4];
    if (lane == 63) wsum[w] = x;
    __syncthreads();
    int wpre = 0;
#pragma unroll
    for (int k = 0; k < 4; k++)
        if (k < w) wpre += wsum[k];
    if (tid < NP) partials[tid] = x - v + wpre;
}

__global__ __launch_bounds__(256) void scanC_kernel(int* __restrict__ offs,
                                                    const int* __restrict__ partials,
                                                    int N, int E) {
    int i = blockIdx.x * 256 + threadIdx.x;
    if (i < N) offs[i] += partials[blockIdx.x];
    if (i == 0) offs[N] = E;
}

__global__ void posfix_kernel(const int* __restrict__ dst,
                              const int* __restrict__ offs,
                              const int* __restrict__ parthist,
                              int* __restrict__ lrank, int E, int CH, int RSZ) {
    int i = blockIdx.x * 256 + threadIdx.x;
    if (i < E) {
        int d = dst[i];
        int c = i / CH;
        int r = d / RSZ;
        int li = d - r * RSZ;
        lrank[i] += offs[d] + parthist[(size_t)(r * NCHUNK + c) * RSZ + li];
    }
}

__global__ __launch_bounds__(256) void scatter_ranged_kernel(
    const int* __restrict__ src, const int* __restrict__ pos,
    int* __restrict__ csr_src, int E) {
    int range = blockIdx.x & 7;
    int chunk = blockIdx.x >> 3;
    int base = chunk * SCH + threadIdx.x;
    int lo = (int)(((long long)range * E) >> 3);
    int hi = (int)(((long long)(range + 1) * E) >> 3);
#pragma unroll
    for (int k = 0; k < SCH / 256; k++) {
        int i = base + k * 256;
        if (i < E) {
            int p = pos[i];
            if (p >= lo && p < hi) csr_src[p] = src[i];
        }
    }
}

// ---------------------------------------------------------------------------
// MFMA GEMM: C[M,128] = A[M,128] @ B[128,128], B transposed bf16 (BT[n][k]).
// Block = 4 waves, each wave 16 rows x 128 cols.
// ELER: one extra 16x16x32 MFMA chain vs the W-projected ALR table computes
// el (cols 0-3) and er (cols 4-7) for the wave's 16 rows.
// ---------------------------------------------------------------------------
template <bool A_FP32, bool OUT_BF16, bool BIAS, bool ELER>
__global__ __launch_bounds__(256) void mfma_gemm_kernel(
    const void* __restrict__ Av, const ushort* __restrict__ BT,
    const float* __restrict__ bias, const ushort* __restrict__ ALR,
    void* __restrict__ Cv, float* __restrict__ el, float* __restrict__ er, int M) {
    int wid = threadIdx.x >> 6;
    int lane = threadIdx.x & 63;
    int row0 = blockIdx.x * 64 + wid * 16;
    int rsub = lane & 15;
    int kg = lane >> 4;
    int row = row0 + rsub;
    int rowc = (row < M) ? row : (M - 1);

    bf16x8 af[4];
    if (A_FP32) {
        const float* A = (const float*)Av;
        const float* ap = A + (size_t)rowc * 128 + kg * 8;
#pragma unroll
        for (int ks = 0; ks < 4; ks++) {
            float4 lo = *(const float4*)(ap + ks * 32);
            float4 hi = *(const float4*)(ap + ks * 32 + 4);
            bf16x8 v;
            v[0] = (short)f2bf(lo.x); v[1] = (short)f2bf(lo.y);
            v[2] = (short)f2bf(lo.z); v[3] = (short)f2bf(lo.w);
            v[4] = (short)f2bf(hi.x); v[5] = (short)f2bf(hi.y);
            v[6] = (short)f2bf(hi.z); v[7] = (short)f2bf(hi.w);
            af[ks] = v;
        }
    } else {
        const ushort* A = (const ushort*)Av;
        const ushort* ap = A + (size_t)rowc * 128 + kg * 8;
#pragma unroll
        for (int ks = 0; ks < 4; ks++) af[ks] = *(const bf16x8*)(ap + ks * 32);
    }

    f32x4 acc[8];
#pragma unroll
    for (int ct = 0; ct < 8; ct++) acc[ct] = (f32x4){0.f, 0.f, 0.f, 0.f};

    const ushort* bp = BT + (size_t)rsub * 128 + kg * 8;
#pragma unroll
    for (int ks = 0; ks < 4; ks++) {
#pragma unroll
        for (int ct = 0; ct < 8; ct++) {
            bf16x8 bf = *(const bf16x8*)(bp + (size_t)ct * 16 * 128 + ks * 32);
            acc[ct] = __builtin_amdgcn_mfma_f32_16x16x32_bf16(af[ks], bf, acc[ct], 0, 0, 0);
        }
    }

    f32x4 acce = (f32x4){0.f, 0.f, 0.f, 0.f};
    if (ELER) {
        const ushort* ep = ALR + rsub * 128 + kg * 8;
#pragma unroll
        for (int ks = 0; ks < 4; ks++) {
            bf16x8 eb = *(const bf16x8*)(ep + ks * 32);
            acce = __builtin_amdgcn_mfma_f32_16x16x32_bf16(af[ks], eb, acce, 0, 0, 0);
        }
    }

    if (row0 >= M) return;

#pragma unroll
    for (int ct = 0; ct < 8; ct++) {
        int col = ct * 16 + rsub;
        float bv = BIAS ? bias[col] : 0.f;
#pragma unroll
        for (int r = 0; r < 4; r++) {
            int gr = row0 + kg * 4 + r;
            if (gr < M) {
                float v = acc[ct][r] + bv;
                if (OUT_BF16) ((ushort*)Cv)[(size_t)gr * 128 + col] = f2bf(v);
                else          ((float*)Cv)[(size_t)gr * 128 + col] = v;
            }
        }
    }

    if (ELER && rsub < 8) {
#pragma unroll
        for (int r = 0; r < 4; r++) {
            int gr = row0 + kg * 4 + r;
            if (gr < M) {
                if (rsub < 4) el[(size_t)gr * 4 + rsub] = acce[r];
                else          er[(size_t)gr * 4 + (rsub - 4)] = acce[r];
            }
        }
    }
}

// ---------------------------------------------------------------------------
// Aggregate (R15-proven): 16 lanes per node (4 nodes/wave, 16 nodes/block).
// Fast path (deg<=64): pass1 stashes (sv, leaky-logit[4]) in LDS during the
// online softmax; after the reduce each lane converts its stashed logits to
// FINAL ALPHAS in LDS (wave-synchronous within the 16-lane group). Pass2:
// 8-edge batches — alpha from LDS + 8 independent 16B feat gathers; no exp
// in loop. Slow path (deg>64): 4-edge shfl batches.
// ---------------------------------------------------------------------------
template <bool F32OUT>
__global__ __launch_bounds__(256) void aggregate_kernel(
    const ushort* __restrict__ featb, const float* __restrict__ el,
    const float* __restrict__ er, const float* __restrict__ bias,
    const int* __restrict__ offsets, const int* __restrict__ csr_src,
    void* __restrict__ outv, int N) {
    __shared__ int   s_sv[16][MAXD + 1];        // +1 pad: group stride 65
    __shared__ float s_lg[16][MAXD + 1][4];
    int tid = threadIdx.x;
    int gl = tid & 15;
    int g  = tid >> 4;
    int lane = tid & 63;
    int n = blockIdx.x * 16 + g;
    if (n >= N) return;
    int start = offsets[n], end = offsets[n + 1];
    int deg = end - start;
    bool fast = (deg <= MAXD);

    float4 erv = *(const float4*)(er + (size_t)n * 4);
    float er_h[4] = {erv.x, erv.y, erv.z, erv.w};

    float m[4], s[4];
#pragma unroll
    for (int h = 0; h < 4; h++) { m[h] = -1e30f; s[h] = 0.f; }

    for (int e = start + gl; e < end; e += 16) {
        int sv = csr_src[e];
        float4 ev = *(const float4*)(el + (size_t)sv * 4);
        float elh[4] = {ev.x, ev.y, ev.z, ev.w};
        int idx = e - start;
        if (fast) s_sv[g][idx] = sv;
#pragma unroll
        for (int h = 0; h < 4; h++) {
            float v = elh[h] + er_h[h];
            v = (v >= 0.f) ? v : NEG_SLOPE * v;
            if (fast) s_lg[g][idx][h] = v;
            float mn = fmaxf(m[h], v);
            s[h] = s[h] * __expf(m[h] - mn) + __expf(v - mn);
            m[h] = mn;
        }
    }
#pragma unroll
    for (int off = 1; off < 16; off <<= 1) {
#pragma unroll
        for (int h = 0; h < 4; h++) {
            float mo = __shfl_xor(m[h], off);
            float so = __shfl_xor(s[h], off);
            float mn = fmaxf(m[h], mo);
            s[h] = s[h] * __expf(m[h] - mn) + so * __expf(mo - mn);
            m[h] = mn;
        }
    }

    int h0 = gl >> 2;
    int c0 = gl * 8;
    float acc[8] = {};

    if (fast) {
        float rz[4];
#pragma unroll
        for (int h = 0; h < 4; h++) rz[h] = (deg > 0) ? 1.0f / s[h] : 0.f;
        for (int e = gl; e < deg; e += 16) {
#pragma unroll
            for (int h = 0; h < 4; h++)
                s_lg[g][e][h] = __expf(s_lg[g][e][h] - m[h]) * rz[h];
        }
        for (int e0 = 0; e0 < deg; e0 += 8) {
            int nb = deg - e0; if (nb > 8) nb = 8;
            float av[8]; int svv[8];
#pragma unroll
            for (int jj = 0; jj < 8; jj++) {
                int idx = (jj < nb) ? (e0 + jj) : e0;
                svv[jj] = s_sv[g][idx];
                av[jj] = (jj < nb) ? s_lg[g][idx][h0] : 0.f;
            }
#pragma unroll
            for (int jj = 0; jj < 8; jj++) {
                uint4 f0 = *(const uint4*)(featb + (size_t)svv[jj] * 128 + c0);
                acc[0] = fmaf(av[jj], bf2f(f0.x & 0xFFFF), acc[0]);
                acc[1] = fmaf(av[jj], bf2f(f0.x >> 16),    acc[1]);
                acc[2] = fmaf(av[jj], bf2f(f0.y & 0xFFFF), acc[2]);
                acc[3] = fmaf(av[jj], bf2f(f0.y >> 16),    acc[3]);
                acc[4] = fmaf(av[jj], bf2f(f0.z & 0xFFFF), acc[4]);
                acc[5] = fmaf(av[jj], bf2f(f0.z >> 16),    acc[5]);
                acc[6] = fmaf(av[jj], bf2f(f0.w & 0xFFFF), acc[6]);
                acc[7] = fmaf(av[jj], bf2f(f0.w >> 16),    acc[7]);
            }
        }
    } else {
        float mh  = sel4(h0, m[0], m[1], m[2], m[3]);
        float sh  = sel4(h0, s[0], s[1], s[2], s[3]);
        float rzh = (deg > 0) ? 1.0f / sh : 0.f;
        int j = gl & 3;
        float erh = sel4(h0, er_h[0], er_h[1], er_h[2], er_h[3]);
        int bidx = lane & 60;
        for (int e = start; e < end; e += 4) {
            int rem = end - e;
            int ej = e + ((j < rem) ? j : 0);
            int svj = csr_src[ej];
            float v = el[(size_t)svj * 4 + h0] + erh;
            v = (v >= 0.f) ? v : NEG_SLOPE * v;
            float a = __expf(v - mh) * rzh;
            if (j >= rem) a = 0.f;
#pragma unroll
            for (int jj = 0; jj < 4; jj++) {
                float ajj = __shfl(a, bidx | jj);
                int svjj  = __shfl(svj, bidx | jj);
                uint4 f0 = *(const uint4*)(featb + (size_t)svjj * 128 + c0);
                acc[0] = fmaf(ajj, bf2f(f0.x & 0xFFFF), acc[0]);
                acc[1] = fmaf(ajj, bf2f(f0.x >> 16),    acc[1]);
                acc[2] = fmaf(ajj, bf2f(f0.y & 0xFFFF), acc[2]);
                acc[3] = fmaf(ajj, bf2f(f0.y >> 16),    acc[3]);
                acc[4] = fmaf(ajj, bf2f(f0.z & 0xFFFF), acc[4]);
                acc[5] = fmaf(ajj, bf2f(f0.z >> 16),    acc[5]);
                acc[6] = fmaf(ajj, bf2f(f0.w & 0xFFFF), acc[6]);
                acc[7] = fmaf(ajj, bf2f(f0.w >> 16),    acc[7]);
            }
        }
    }

    float4 b0 = *(const float4*)(bias + c0);
    float4 b1 = *(const float4*)(bias + c0 + 4);
    float o[8];
    o[0] = acc[0] + b0.x; o[1] = acc[1] + b0.y; o[2] = acc[2] + b0.z; o[3] = acc[3] + b0.w;
    o[4] = acc[4] + b1.x; o[5] = acc[5] + b1.y; o[6] = acc[6] + b1.z; o[7] = acc[7] + b1.w;
    if (F32OUT) {
        float* outf = (float*)outv;
        float4 w0, w1;
        w0.x = o[0]; w0.y = o[1]; w0.z = o[2]; w0.w = o[3];
        w1.x = o[4]; w1.y = o[5]; w1.z = o[6]; w1.w = o[7];
        *(float4*)(outf + (size_t)n * 128 + c0) = w0;
        *(float4*)(outf + (size_t)n * 128 + c0 + 4) = w1;
    } else {
        ushort* outb = (ushort*)outv;
        uint4 p;
        p.x = (uint)f2bf(o[0]) | ((uint)f2bf(o[1]) << 16);
        p.y = (uint)f2bf(o[2]) | ((uint)f2bf(o[3]) << 16);
        p.z = (uint)f2bf(o[4]) | ((uint)f2bf(o[5]) << 16);
        p.w = (uint)f2bf(o[6]) | ((uint)f2bf(o[7]) << 16);
        *(uint4*)(outb + (size_t)n * 128 + c0) = p;
    }
}

// ---------------------------------------------------------------------------
extern "C" void kernel_launch(void* const* d_in, const int* in_sizes, int n_in,
                              void* d_out, int out_size, void* d_ws, size_t ws_size,
                              hipStream_t stream) {
    const float* x   = (const float*)d_in[0];
    const int*   src = (const int*)d_in[1];
    const int*   dst = (const int*)d_in[2];
    const float* W1  = (const float*)d_in[3];
    const float* al1 = (const float*)d_in[4];
    const float* ar1 = (const float*)d_in[5];
    const float* b1  = (const float*)d_in[6];
    const float* W2  = (const float*)d_in[7];
    const float* al2 = (const float*)d_in[8];
    const float* ar2 = (const float*)d_in[9];
    const float* b2  = (const float*)d_in[10];
    const float* Wp  = (const float*)d_in[11];
    const float* bp  = (const float*)d_in[12];

    const int N = in_sizes[0] / F;      // 50000
    const int E = in_sizes[1];          // 800000

    float* h_out = (float*)d_out;               // [N,128]  (layer-2 output h, checked)
    float* p_out = h_out + (size_t)N * F;       // [N,128]  (projection output, checked)

    const int NB  = (N + 255) / 256;
    const int ECS = (E + SCH - 1) / SCH;        // scatter chunks
    const int CH  = (E + NCHUNK - 1) / NCHUNK;  // hist chunk size
    const int RSZ = (N + 7) / 8;                // nodes per range (<= RSZ_MAX)

    // workspace carve
    char* w = (char*)d_ws;
    ushort* featb   = (ushort*)w;                               // N*128 bf16
    ushort* h1b     = featb + (size_t)N * F;                    // N*128 bf16
    float* el       = (float*)(h1b + (size_t)N * F);            // N*4
    float* er       = el + (size_t)N * 4;                       // N*4
    int*   offs     = (int*)(er + (size_t)N * 4);               // N+1
    int*   lrank    = offs + (N + 1);                           // E (becomes pos)
    int*   csrsrc   = lrank + E;                                // E
    int*   partials = csrsrc + E;                               // 256
    int*   parthist = partials + 256;                           // 8*NCHUNK*RSZ
    ushort* WT      = (ushort*)(parthist + (size_t)8 * NCHUNK * RSZ);

    ushort* WT1  = WT;
    ushort* WT2  = WT + 128 * 128;
    ushort* WTp  = WT + 2 * 128 * 128;
    ushort* ALR1 = WT + 3 * 128 * 128;
    ushort* ALR2 = ALR1 + 16 * 128;

    // --- atomic-free CSR build + weight prep ---
    hist_lds_wtrans_kernel<<<8 * NCHUNK + 5, 256, 0, stream>>>(
        dst, parthist, lrank, W1, W2, Wp, al1, ar1, al2, ar2, WT, E, N, CH, RSZ);
    scanA_kernel<<<NB, 256, 0, stream>>>(parthist, offs, partials, N, RSZ);
    scanB_kernel<<<1, 256, 0, stream>>>(partials, NB);
    scanC_kernel<<<NB, 256, 0, stream>>>(offs, partials, N, E);
    posfix_kernel<<<(E + 255) / 256, 256, 0, stream>>>(dst, offs, parthist, lrank, E, CH, RSZ);
    scatter_ranged_kernel<<<8 * ECS, 256, 0, stream>>>(src, lrank, csrsrc, E);

    int ggrid = (N + 63) / 64;
    int agrid = (N + 15) / 16;

    // --- layer 1 (GEMM + MFMA el/er) ---
    mfma_gemm_kernel<true, true, false, true><<<ggrid, 256, 0, stream>>>(
        x, WT1, nullptr, ALR1, featb, el, er, N);
    aggregate_kernel<false><<<agrid, 256, 0, stream>>>(
        featb, el, er, b1, offs, csrsrc, h1b, N);

    // --- layer 2 (GEMM + MFMA el/er) ---
    mfma_gemm_kernel<false, true, false, true><<<ggrid, 256, 0, stream>>>(
        h1b, WT2, nullptr, ALR2, featb, el, er, N);
    aggregate_kernel<true><<<agrid, 256, 0, stream>>>(
        featb, el, er, b2, offs, csrsrc, h_out, N);

    // --- projection (reads fp32 h_out, converts to bf16 in-register) ---
    mfma_gemm_kernel<true, false, true, false><<<ggrid, 256, 0, stream>>>(
        h_out, WTp, bp, nullptr, p_out, nullptr, nullptr, N);
}